// Round 9
// baseline (527.756 us; speedup 1.0000x reference)
//
#include <hip/hip_runtime.h>
#include <hip/hip_bf16.h>
#include <math.h>

#define B 512
#define T 64
#define NL 32
#define LAT 64
#define HID 128
#define DIN 65
#define G3 384
#define FSCALE 365.0f
#define MAXGRID 128

// ws layout (float index)
#define WS_MIN   0   // int
#define WS_MAX   1   // int
#define WS_NIT   2   // int
#define WS_KL    3
#define WS_RE    4
#define WS_NO    5
#define WS_GRID  8                 // MAXGRID floats
#define WS_Z0    (WS_GRID + MAXGRID)
#define WS_YS    (WS_Z0 + B*LAT)   // MAXGRID * B * LAT floats
// nit <= 111 always; ys rows >=120 never written; reuse tail for W31/b31.
#define WS_W31   (WS_YS + 120*B*LAT)
#define WS_B31   (WS_W31 + HID*HID)

typedef __attribute__((ext_vector_type(8))) __bf16 bf16x8;
typedef __attribute__((ext_vector_type(4))) float f32x4;

// Bank de-alias swizzle: rows 8 apart alias with any 16B-multiple stride
// (stride*8 % 128B == 0). XOR byte-bit-5 on row>>3 separates them while
// keeping 16B alignment. (base+o)^sw == (base^sw)+o for o<16, sw bits>=4.
#define SWZ(row) ((((row)>>3)&1)<<5)

static __device__ __forceinline__ float tanh_fast(float x){
    float t = __builtin_amdgcn_exp2f(x * 2.8853900817779268f);
    return 1.0f - 2.0f * __builtin_amdgcn_rcpf(t + 1.0f);
}
static __device__ __forceinline__ float sigmoid_fast(float x){
    return __builtin_amdgcn_rcpf(1.0f + __builtin_amdgcn_exp2f(-1.4426950408889634f * x));
}
// LDS-only barrier: drains lgkmcnt but not vmcnt.
static __device__ __forceinline__ void bar_lds(){
    asm volatile("" ::: "memory");
    asm volatile("s_waitcnt lgkmcnt(0)" ::: "memory");
    __builtin_amdgcn_s_barrier();
    asm volatile("" ::: "memory");
}

// ---------------- kernel 1: min/max + accumulators + integration grid ----------------
__global__ void k_setup(const int* __restrict__ tp, float* wsf){
    int* wsi = (int*)wsf;
    __shared__ int smin[256], smax[256];
    int tid = threadIdx.x;
    int mn = 2147483647, mx = -2147483647-1;
    for (int i = tid; i < B*T; i += 256){ int v = tp[i]; mn = min(mn,v); mx = max(mx,v); }
    smin[tid]=mn; smax[tid]=mx; __syncthreads();
    for (int s=128; s>0; s>>=1){
        if (tid<s){ smin[tid]=min(smin[tid],smin[tid+s]); smax[tid]=max(smax[tid],smax[tid+s]); }
        __syncthreads();
    }
    float t0f = (float)smin[0] / FSCALE;
    float t1f = (float)smax[0] / FSCALE;
    double t0d = (double)t0f, t1d = (double)t1f;
    int nit = (int)ceil((t1d-t0d)/0.05 + 1.0);
    if (nit < 1) nit = 1;
    if (nit > MAXGRID) nit = MAXGRID;
    if (tid==0){
        wsi[WS_NIT] = nit;
        wsf[WS_KL]=0.f; wsf[WS_RE]=0.f; wsf[WS_NO]=0.f;
    }
    if (tid < nit){
        double g = (double)tid * 0.05 + t0d;
        if (tid == nit-1 && g > t1d) g = t1d;
        wsf[WS_GRID + tid] = (float)g;
    }
}

// ---------------- kernel 2b: W31 = W3 @ W1 (f32), b31 = b3 @ W1 ----------------
__global__ __launch_bounds__(256) void k_w31(
    const float* __restrict__ W1, const float* __restrict__ W3,
    const float* __restrict__ b3, float* wsf)
{
    int gid = blockIdx.x*256 + threadIdx.x;   // 0..4095
    int k = gid >> 5, n0 = (gid & 31)*4;
    float4 acc = {0.f,0.f,0.f,0.f};
    #pragma unroll 8
    for (int l=0;l<64;++l){
        float w3v = W3[k*LAT + l];
        float4 w1v = *(const float4*)&W1[l*HID + n0];
        acc.x = fmaf(w3v, w1v.x, acc.x);
        acc.y = fmaf(w3v, w1v.y, acc.y);
        acc.z = fmaf(w3v, w1v.z, acc.z);
        acc.w = fmaf(w3v, w1v.w, acc.w);
    }
    *(float4*)&wsf[WS_W31 + k*HID + n0] = acc;
    if (blockIdx.x==0 && threadIdx.x < HID){
        int n = threadIdx.x; float a = 0.f;
        #pragma unroll 8
        for (int l=0;l<64;++l) a = fmaf(b3[l], W1[l*HID+n], a);
        wsf[WS_B31 + n] = a;
    }
}

// ---------------- kernel 3: GRU encoder via MFMA (16 rows/block, 8 waves) ----------------
// xh stride 464B; all accesses XOR-swizzled with SWZ(row) (bank de-alias).
__global__ __launch_bounds__(512) void k_gru(
    const float* __restrict__ obs, const float* __restrict__ eps,
    const float* __restrict__ Wih, const float* __restrict__ Whh,
    const float* __restrict__ bih, const float* __restrict__ bhh,
    const float* __restrict__ Wmu, const float* __restrict__ bmu,
    const float* __restrict__ Wlv, const float* __restrict__ blv,
    const int* __restrict__ maskI, const int* __restrict__ tp,
    float* wsf)
{
    const int b0 = blockIdx.x * 16;
    const int tid = threadIdx.x;
    const int w = tid >> 6, lane = tid & 63;
    const int g = lane >> 4, c = lane & 15;
    const int xr = tid >> 5, xl = tid & 31;

    __shared__ __align__(16) __bf16 xh[16][232];   // stride 464B
    __shared__ int   tps[16][64];
    __shared__ float dts[16];
    __shared__ float lvs[16][64];
    __shared__ float red[8];
    char* xbase = (char*)&xh[0][0];
    #define XH_RD(row, bytecol) (*(const bf16x8*)(xbase + (row)*464 + ((bytecol) ^ SWZ(row))))
    #define XH_WPTR(row, bytecol) ((__bf16*)(xbase + (row)*464 + ((bytecol) ^ SWZ(row))))

    ((int2*)tps)[tid] = ((const int2*)(tp + (size_t)b0*T))[tid];
    {
        unsigned* xz = (unsigned*)xbase;
        #pragma unroll
        for (int i=0;i<1856;i+=512) xz[i+tid] = 0u;
    }

    bf16x8 wr[6], wz[6], wi[2], wh[4];
    #pragma unroll
    for (int q=0;q<6;++q){
        int kt = q<2 ? q : q+1;
        #pragma unroll
        for (int e=0;e<8;++e){
            int k = kt*32 + g*8 + e;
            float vr, vz;
            if (k < 64){ vr = Wih[k*G3 + 16*w+c];      vz = Wih[k*G3 + 128+16*w+c]; }
            else       { vr = Whh[(k-96)*G3 + 16*w+c]; vz = Whh[(k-96)*G3 + 128+16*w+c]; }
            wr[q][e] = (__bf16)vr; wz[q][e] = (__bf16)vz;
        }
    }
    #pragma unroll
    for (int q=0;q<2;++q)
        #pragma unroll
        for (int e=0;e<8;++e)
            wi[q][e] = (__bf16)Wih[(q*32+g*8+e)*G3 + 256+16*w+c];
    #pragma unroll
    for (int q=0;q<4;++q)
        #pragma unroll
        for (int e=0;e<8;++e)
            wh[q][e] = (__bf16)Whh[(q*32+g*8+e)*G3 + 256+16*w+c];
    const float wdr = Wih[64*G3 + 16*w+c];
    const float wdz = Wih[64*G3 + 128+16*w+c];
    const float wdn = Wih[64*G3 + 256+16*w+c];
    const float rb  = bih[16*w+c]     + bhh[16*w+c];
    const float zb  = bih[128+16*w+c] + bhh[128+16*w+c];
    const float inb = bih[256+16*w+c];
    const float hnb = bhh[256+16*w+c];

    __syncthreads();

    {
        float mv = (float)maskI[((size_t)(b0+xr)*T + 63)*NL + xl];
        float ov = obs[((size_t)(b0+xr)*T + 63)*NL + xl];
        *XH_WPTR(xr, 2*xl)      = (__bf16)(ov*mv);
        *XH_WPTR(xr, 64 + 2*xl) = (__bf16)mv;
        if (xl==0) dts[xr] = (float)(tps[xr][63]-tps[xr][62]);
    }
    float ovP = 0.f, mvP = 0.f;
    {
        mvP = (float)maskI[((size_t)(b0+xr)*T + 62)*NL + xl];
        ovP = obs[((size_t)(b0+xr)*T + 62)*NL + xl];
    }

    float hold[4] = {0.f,0.f,0.f,0.f};

    for (int s=0;s<T;++s){
        bar_lds();
        bf16x8 A0 = XH_RD(c, 0   + 16*g);
        bf16x8 A1 = XH_RD(c, 64  + 16*g);
        bf16x8 A2 = XH_RD(c, 192 + 16*g);
        bf16x8 A3 = XH_RD(c, 256 + 16*g);
        bf16x8 A4 = XH_RD(c, 320 + 16*g);
        bf16x8 A5 = XH_RD(c, 384 + 16*g);
        const float dt0=dts[4*g], dt1=dts[4*g+1], dt2=dts[4*g+2], dt3=dts[4*g+3];
        float ovN=0.f, mvN=0.f; const int t2 = 61-s;
        if (t2 >= 0){
            mvN = (float)maskI[((size_t)(b0+xr)*T + t2)*NL + xl];
            ovN = obs[((size_t)(b0+xr)*T + t2)*NL + xl];
        }
        f32x4 racc={0,0,0,0}, zacc={0,0,0,0}, inacc={0,0,0,0}, hnacc={0,0,0,0};
        racc  = __builtin_amdgcn_mfma_f32_16x16x32_bf16(A0, wr[0], racc, 0,0,0);
        zacc  = __builtin_amdgcn_mfma_f32_16x16x32_bf16(A0, wz[0], zacc, 0,0,0);
        inacc = __builtin_amdgcn_mfma_f32_16x16x32_bf16(A0, wi[0], inacc,0,0,0);
        hnacc = __builtin_amdgcn_mfma_f32_16x16x32_bf16(A2, wh[0], hnacc,0,0,0);
        racc  = __builtin_amdgcn_mfma_f32_16x16x32_bf16(A1, wr[1], racc, 0,0,0);
        zacc  = __builtin_amdgcn_mfma_f32_16x16x32_bf16(A1, wz[1], zacc, 0,0,0);
        inacc = __builtin_amdgcn_mfma_f32_16x16x32_bf16(A1, wi[1], inacc,0,0,0);
        hnacc = __builtin_amdgcn_mfma_f32_16x16x32_bf16(A3, wh[1], hnacc,0,0,0);
        racc  = __builtin_amdgcn_mfma_f32_16x16x32_bf16(A2, wr[2], racc, 0,0,0);
        zacc  = __builtin_amdgcn_mfma_f32_16x16x32_bf16(A2, wz[2], zacc, 0,0,0);
        hnacc = __builtin_amdgcn_mfma_f32_16x16x32_bf16(A4, wh[2], hnacc,0,0,0);
        racc  = __builtin_amdgcn_mfma_f32_16x16x32_bf16(A3, wr[3], racc, 0,0,0);
        zacc  = __builtin_amdgcn_mfma_f32_16x16x32_bf16(A3, wz[3], zacc, 0,0,0);
        hnacc = __builtin_amdgcn_mfma_f32_16x16x32_bf16(A5, wh[3], hnacc,0,0,0);
        racc  = __builtin_amdgcn_mfma_f32_16x16x32_bf16(A4, wr[4], racc, 0,0,0);
        zacc  = __builtin_amdgcn_mfma_f32_16x16x32_bf16(A4, wz[4], zacc, 0,0,0);
        racc  = __builtin_amdgcn_mfma_f32_16x16x32_bf16(A5, wr[5], racc, 0,0,0);
        zacc  = __builtin_amdgcn_mfma_f32_16x16x32_bf16(A5, wz[5], zacc, 0,0,0);
        float hnew[4]; const float dtv[4] = {dt0,dt1,dt2,dt3};
        #pragma unroll
        for (int j=0;j<4;++j){
            float dv = dtv[j];
            float r  = sigmoid_fast(racc[j] + rb + dv*wdr);
            float zg = sigmoid_fast(zacc[j] + zb + dv*wdz);
            float n  = tanh_fast(inacc[j] + inb + dv*wdn + r*(hnacc[j] + hnb));
            float hv = (1.f - zg)*n + zg*hold[j];
            hold[j] = hv; hnew[j] = hv;
        }
        bar_lds();
        #pragma unroll
        for (int j=0;j<4;++j)
            *XH_WPTR(4*g+j, 192 + 2*(16*w+c)) = (__bf16)hnew[j];
        if (s < T-1){
            const int tn = 62 - s;
            *XH_WPTR(xr, 2*xl)      = (__bf16)(ovP*mvP);
            *XH_WPTR(xr, 64 + 2*xl) = (__bf16)mvP;
            if (xl==0) dts[xr] = (tn>0) ? (float)(tps[xr][tn]-tps[xr][tn-1]) : 0.f;
        }
        ovP = ovN; mvP = mvN;
    }
    __syncthreads();

    const int col4 = 16*(w&3)+c;
    bf16x8 Ah0 = XH_RD(c, 192 + 0   + 16*g);
    bf16x8 Ah1 = XH_RD(c, 192 + 64  + 16*g);
    bf16x8 Ah2 = XH_RD(c, 192 + 128 + 16*g);
    bf16x8 Ah3 = XH_RD(c, 192 + 192 + 16*g);
    const float* Wm = (w<4)? Wmu : Wlv;
    f32x4 acc={0,0,0,0};
    {
        bf16x8 bf0,bf1,bf2,bf3;
        #pragma unroll
        for (int e=0;e<8;++e){
            bf0[e] = (__bf16)Wm[(0*32+g*8+e)*LAT + col4];
            bf1[e] = (__bf16)Wm[(1*32+g*8+e)*LAT + col4];
            bf2[e] = (__bf16)Wm[(2*32+g*8+e)*LAT + col4];
            bf3[e] = (__bf16)Wm[(3*32+g*8+e)*LAT + col4];
        }
        acc = __builtin_amdgcn_mfma_f32_16x16x32_bf16(Ah0, bf0, acc, 0,0,0);
        acc = __builtin_amdgcn_mfma_f32_16x16x32_bf16(Ah1, bf1, acc, 0,0,0);
        acc = __builtin_amdgcn_mfma_f32_16x16x32_bf16(Ah2, bf2, acc, 0,0,0);
        acc = __builtin_amdgcn_mfma_f32_16x16x32_bf16(Ah3, bf3, acc, 0,0,0);
    }
    const float mbias = (w<4)? bmu[col4] : blv[col4];
    if (w>=4){
        #pragma unroll
        for (int j=0;j<4;++j) lvs[4*g+j][col4] = acc[j] + mbias;
    }
    __syncthreads();
    if (w<4){
        float kl = 0.f;
        #pragma unroll
        for (int j=0;j<4;++j){
            float mu = acc[j] + mbias;
            float lv = lvs[4*g+j][col4];
            int row = b0 + 4*g + j;
            float z0 = mu + eps[(size_t)row*LAT + col4]*expf(0.5f*lv);
            wsf[WS_Z0 + (size_t)row*LAT + col4] = z0;
            wsf[WS_YS + (size_t)row*LAT + col4] = z0;
            kl += 1.f + lv - mu*mu - expf(lv);
        }
        #pragma unroll
        for (int off=32; off>0; off>>=1) kl += __shfl_xor(kl, off);
        if (lane==0) red[w] = kl;
    }
    __syncthreads();
    if (tid==0) atomicAdd(&wsf[WS_KL], red[0]+red[1]+red[2]+red[3]);
    #undef XH_RD
    #undef XH_WPTR
}

// ---------------- kernel 4: RK4 ODE, 2-phase fused, 8 waves, swizzled LDS ----------
__global__ __launch_bounds__(512) void k_ode(
    const float* __restrict__ W1, const float* __restrict__ b1,
    const float* __restrict__ W2, const float* __restrict__ b2,
    const float* __restrict__ W3, const float* __restrict__ b3,
    float* wsf)
{
    const int b0 = blockIdx.x * 16;
    const int tid = threadIdx.x;
    const int w = tid >> 6, lane = tid & 63;
    const int g = lane >> 4, c = lane & 15;
    const int hc = 16*w + c;
    const int lc = 16*(w&3) + c;
    const int* wsi = (const int*)wsf;
    const int nit = wsi[WS_NIT];

    __shared__ __align__(16) __bf16 Gl[16][136];   // stride 272B
    __shared__ __align__(16) __bf16 Hl[16][136];
    __shared__ float gls[MAXGRID];
    char* gbase = (char*)&Gl[0][0];
    char* hbase = (char*)&Hl[0][0];
    #define LDS_RD(base, row, bytecol) (*(const bf16x8*)((base) + (row)*272 + ((bytecol) ^ SWZ(row))))
    #define LDS_WPTR(base, row, bytecol) ((__bf16*)((base) + (row)*272 + ((bytecol) ^ SWZ(row))))

    bf16x8 w2f[4], w31f[4], w3f[4];
    #pragma unroll
    for (int q=0;q<4;++q)
        #pragma unroll
        for (int e=0;e<8;++e){
            w2f[q][e]  = (__bf16)W2[(q*32+g*8+e)*HID + hc];
            w31f[q][e] = (__bf16)wsf[WS_W31 + (q*32+g*8+e)*HID + hc];
            w3f[q][e]  = (__bf16)W3[(q*32+g*8+e)*LAT + lc];
        }
    const float b1v  = b1[hc];
    const float b2v  = b2[hc];
    const float b31v = wsf[WS_B31 + hc];
    const float b3v  = b3[lc];

    for (int kk=tid; kk<MAXGRID; kk+=512) gls[kk]=wsf[WS_GRID+kk];

    // stage z0 (swizzled 4B writes) + y init
    {
        int r = tid >> 5, l0 = (tid & 31)*2;
        float2 zv = *(const float2*)&wsf[WS_Z0 + (size_t)(b0+r)*LAT + l0];
        __bf16* p = LDS_WPTR(gbase, r, 2*l0);
        p[0] = (__bf16)zv.x;
        p[1] = (__bf16)zv.y;
    }
    float y[4];
    #pragma unroll
    for (int j=0;j<4;++j)
        y[j] = wsf[WS_Z0 + (size_t)(b0+4*g+j)*LAT + lc];
    __syncthreads();

    // U = z0 @ W1
    f32x4 U;
    {
        bf16x8 az0 = LDS_RD(gbase, c, 16*g);
        bf16x8 az1 = LDS_RD(gbase, c, 64 + 16*g);
        bf16x8 wf0, wf1;
        #pragma unroll
        for (int e=0;e<8;++e){
            wf0[e] = (__bf16)W1[(g*8+e)*HID + hc];
            wf1[e] = (__bf16)W1[(32+g*8+e)*HID + hc];
        }
        f32x4 a = {0.f,0.f,0.f,0.f};
        a = __builtin_amdgcn_mfma_f32_16x16x32_bf16(az0, wf0, a, 0,0,0);
        a = __builtin_amdgcn_mfma_f32_16x16x32_bf16(az1, wf1, a, 0,0,0);
        U = a;
    }
    __syncthreads();

    #pragma unroll
    for (int j=0;j<4;++j)
        *LDS_WPTR(gbase, 4*g+j, 2*hc) = (__bf16)tanh_fast(U[j] + b1v);
    __syncthreads();

    f32x4 Uacc={0,0,0,0}, faccv={0,0,0,0};

    for (int i=0; i<nit-1; ++i){
        const float h = gls[i+1]-gls[i];
        #pragma unroll
        for (int sub=0; sub<4; ++sub){
            // phase B: H2 = tanh(G @ W2 + b2)
            {
                bf16x8 a0 = LDS_RD(gbase, c, 0   + 16*g);
                bf16x8 a1 = LDS_RD(gbase, c, 64  + 16*g);
                bf16x8 a2 = LDS_RD(gbase, c, 128 + 16*g);
                bf16x8 a3 = LDS_RD(gbase, c, 192 + 16*g);
                __builtin_amdgcn_s_setprio(1);
                f32x4 ca={0,0,0,0}, cb={0,0,0,0};
                ca = __builtin_amdgcn_mfma_f32_16x16x32_bf16(a0, w2f[0], ca, 0,0,0);
                cb = __builtin_amdgcn_mfma_f32_16x16x32_bf16(a2, w2f[2], cb, 0,0,0);
                ca = __builtin_amdgcn_mfma_f32_16x16x32_bf16(a1, w2f[1], ca, 0,0,0);
                cb = __builtin_amdgcn_mfma_f32_16x16x32_bf16(a3, w2f[3], cb, 0,0,0);
                __builtin_amdgcn_s_setprio(0);
                #pragma unroll
                for (int j=0;j<4;++j)
                    *LDS_WPTR(hbase, 4*g+j, 2*hc) = (__bf16)tanh_fast(ca[j]+cb[j]+b2v);
            }
            bar_lds();
            // phase C: V' = H2@W31+b31 (all), F = H2@W3+b3 (waves 0-3), RK4
            {
                bf16x8 h0 = LDS_RD(hbase, c, 0   + 16*g);
                bf16x8 h1 = LDS_RD(hbase, c, 64  + 16*g);
                bf16x8 h2 = LDS_RD(hbase, c, 128 + 16*g);
                bf16x8 h3 = LDS_RD(hbase, c, 192 + 16*g);
                __builtin_amdgcn_s_setprio(1);
                f32x4 va={0,0,0,0}, vb={0,0,0,0};
                va = __builtin_amdgcn_mfma_f32_16x16x32_bf16(h0, w31f[0], va, 0,0,0);
                vb = __builtin_amdgcn_mfma_f32_16x16x32_bf16(h2, w31f[2], vb, 0,0,0);
                va = __builtin_amdgcn_mfma_f32_16x16x32_bf16(h1, w31f[1], va, 0,0,0);
                vb = __builtin_amdgcn_mfma_f32_16x16x32_bf16(h3, w31f[3], vb, 0,0,0);
                f32x4 fv = {0,0,0,0};
                if (w < 4){
                    f32x4 fa={0,0,0,0}, fb={0,0,0,0};
                    fa = __builtin_amdgcn_mfma_f32_16x16x32_bf16(h0, w3f[0], fa, 0,0,0);
                    fb = __builtin_amdgcn_mfma_f32_16x16x32_bf16(h2, w3f[2], fb, 0,0,0);
                    fa = __builtin_amdgcn_mfma_f32_16x16x32_bf16(h1, w3f[1], fa, 0,0,0);
                    fb = __builtin_amdgcn_mfma_f32_16x16x32_bf16(h3, w3f[3], fb, 0,0,0);
                    #pragma unroll
                    for (int j=0;j<4;++j) fv[j] = fa[j] + fb[j] + b3v;
                }
                __builtin_amdgcn_s_setprio(0);
                f32x4 V;
                #pragma unroll
                for (int j=0;j<4;++j) V[j] = va[j] + vb[j] + b31v;

                if (sub==0){ Uacc = V; faccv = fv; }
                else if (sub==3){ Uacc += V; faccv += fv; }
                else { Uacc += 2.f*V; faccv += 2.f*fv; }

                if (sub < 3){
                    const float al = (sub==2) ? h : 0.5f*h;
                    #pragma unroll
                    for (int j=0;j<4;++j)
                        *LDS_WPTR(gbase, 4*g+j, 2*hc) = (__bf16)tanh_fast(fmaf(al, V[j], U[j]) + b1v);
                } else {
                    const float h6 = h*(1.0f/6.0f);
                    if (w < 4){
                        #pragma unroll
                        for (int j=0;j<4;++j){
                            y[j] = fmaf(h6, faccv[j], y[j]);
                            wsf[WS_YS + ((size_t)(i+1)*B + (b0+4*g+j))*LAT + lc] = y[j];
                        }
                    }
                    #pragma unroll
                    for (int j=0;j<4;++j){
                        U[j] = fmaf(h6, Uacc[j], U[j]);
                        *LDS_WPTR(gbase, 4*g+j, 2*hc) = (__bf16)tanh_fast(U[j] + b1v);
                    }
                }
            }
            bar_lds();
        }
    }
    #undef LDS_RD
    #undef LDS_WPTR
}

// ---------------- kernel 5: recon + surv merged (1 block per b, 8 waves) ----------------
__global__ __launch_bounds__(512) void k_recon(
    const float* __restrict__ obs, const int* __restrict__ maskI,
    const int* __restrict__ tp, const int* __restrict__ seq,
    const float* __restrict__ Wo1, const float* __restrict__ bo1,
    const float* __restrict__ Wo2, const float* __restrict__ bo2,
    const float* __restrict__ age,
    const float* __restrict__ Ws1, const float* __restrict__ bs1,
    const float* __restrict__ Ws2, const float* __restrict__ bs2,
    float* wsf, float* out)
{
    const int b = blockIdx.x, tid = threadIdx.x;
    const int w = tid >> 6, lane = tid & 63;
    const int g = lane >> 4, c = lane & 15;
    __shared__ __align__(16) __bf16 zbt[64][72];
    __shared__ __align__(16) __bf16 hb[64][136];
    __shared__ float gls[MAXGRID];
    __shared__ float red[16];
    __shared__ float ze[64];
    __shared__ float pred[4];
    const int* wsi=(const int*)wsf;
    const int nit = wsi[WS_NIT];
    for (int i=tid;i<MAXGRID;i+=512) gls[i]=wsf[WS_GRID+i];

    bf16x8 wo1f[2], wo2f[4];
    #pragma unroll
    for (int q=0;q<2;++q)
        #pragma unroll
        for (int e=0;e<8;++e)
            wo1f[q][e] = (__bf16)Wo1[(q*32+g*8+e)*HID + 16*w+c];
    {
        int n = w & 1;
        #pragma unroll
        for (int q=0;q<4;++q)
            #pragma unroll
            for (int e=0;e<8;++e)
                wo2f[q][e] = (__bf16)Wo2[(q*32+g*8+e)*NL + 16*n+c];
    }
    const float bo1v = bo1[16*w+c];
    const float bo2v = bo2[16*(w&1)+c];
    const int sl = seq[b];
    __syncthreads();

    {
        int t = tid >> 3, seg = tid & 7;
        float tq = (float)tp[b*T+t] / FSCALE;
        int lo=0, hi=nit;
        while (lo<hi){ int mid=(lo+hi)>>1; if (gls[mid]<=tq) lo=mid+1; else hi=mid; }
        int k = lo-1; if (k<0) k=0; if (nit>=2 && k>nit-2) k=nit-2; if (nit<2) k=0;
        float wq=0.f;
        if (nit>=2){ float tl=gls[k], tr=gls[k+1]; float den=(tr-tl==0.f)?1.f:(tr-tl); wq=(tq-tl)/den; }
        size_t o0 = (size_t)WS_YS + ((size_t)k*B + b)*LAT + seg*8;
        float4 za0 = *(const float4*)&wsf[o0];
        float4 za1 = *(const float4*)&wsf[o0+4];
        float4 zb0, zb1;
        if (nit>=2){
            zb0 = *(const float4*)&wsf[o0 + (size_t)B*LAT];
            zb1 = *(const float4*)&wsf[o0 + (size_t)B*LAT + 4];
        } else { zb0 = za0; zb1 = za1; }
        __bf16* dst = &zbt[t][seg*8];
        dst[0] = (__bf16)(za0.x*(1.f-wq)+zb0.x*wq);
        dst[1] = (__bf16)(za0.y*(1.f-wq)+zb0.y*wq);
        dst[2] = (__bf16)(za0.z*(1.f-wq)+zb0.z*wq);
        dst[3] = (__bf16)(za0.w*(1.f-wq)+zb0.w*wq);
        dst[4] = (__bf16)(za1.x*(1.f-wq)+zb1.x*wq);
        dst[5] = (__bf16)(za1.y*(1.f-wq)+zb1.y*wq);
        dst[6] = (__bf16)(za1.z*(1.f-wq)+zb1.z*wq);
        dst[7] = (__bf16)(za1.w*(1.f-wq)+zb1.w*wq);
    }
    __syncthreads();

    #pragma unroll
    for (int m=0;m<4;++m){
        f32x4 acc = {0.f,0.f,0.f,0.f};
        bf16x8 a0 = *(const bf16x8*)&zbt[16*m+c][g*8];
        bf16x8 a1 = *(const bf16x8*)&zbt[16*m+c][32+g*8];
        acc = __builtin_amdgcn_mfma_f32_16x16x32_bf16(a0, wo1f[0], acc, 0,0,0);
        acc = __builtin_amdgcn_mfma_f32_16x16x32_bf16(a1, wo1f[1], acc, 0,0,0);
        #pragma unroll
        for (int j=0;j<4;++j)
            hb[16*m+4*g+j][16*w+c] = (__bf16)fmaxf(acc[j] + bo1v, 0.f);
    }
    __syncthreads();

    float esum = 0.f, ncnt = 0.f;
    {
        int m = w >> 1, n = w & 1;
        f32x4 ca = {0.f,0.f,0.f,0.f}, cb = {0.f,0.f,0.f,0.f};
        bf16x8 a0 = *(const bf16x8*)&hb[16*m+c][g*8];
        bf16x8 a1 = *(const bf16x8*)&hb[16*m+c][32+g*8];
        bf16x8 a2 = *(const bf16x8*)&hb[16*m+c][64+g*8];
        bf16x8 a3 = *(const bf16x8*)&hb[16*m+c][96+g*8];
        ca = __builtin_amdgcn_mfma_f32_16x16x32_bf16(a0, wo2f[0], ca, 0,0,0);
        cb = __builtin_amdgcn_mfma_f32_16x16x32_bf16(a2, wo2f[2], cb, 0,0,0);
        ca = __builtin_amdgcn_mfma_f32_16x16x32_bf16(a1, wo2f[1], ca, 0,0,0);
        cb = __builtin_amdgcn_mfma_f32_16x16x32_bf16(a3, wo2f[3], cb, 0,0,0);
        #pragma unroll
        for (int j=0;j<4;++j){
            int t = 16*m + 4*g + j;
            int col = 16*n + c;
            float xh2 = (ca[j]+cb[j]) + bo2v;
            float mv = (float)maskI[(b*T+t)*NL+col] * ((t<sl)?1.f:0.f);
            float d = xh2 - obs[(b*T+t)*NL+col];
            esum = fmaf(mv*d, d, esum);
            ncnt += mv;
        }
    }
    #pragma unroll
    for (int off=32; off>0; off>>=1){
        esum += __shfl_xor(esum, off);
        ncnt += __shfl_xor(ncnt, off);
    }
    if (lane==0){ red[w] = esum; red[8+w] = ncnt; }
    __syncthreads();
    if (tid==0){
        float s=0.f, nn=0.f;
        #pragma unroll
        for (int i=0;i<8;++i){ s += red[i]; nn += red[8+i]; }
        atomicAdd(&wsf[WS_RE], s);
        atomicAdd(&wsf[WS_NO], nn);
    }

    // ---- merged survival head ----
    {
        float tq = (float)tp[b*T + sl-1] / FSCALE;
        int lo=0,hi=nit;
        while(lo<hi){int mid=(lo+hi)>>1; if (gls[mid]<=tq) lo=mid+1; else hi=mid;}
        int k=lo-1; if(k<0)k=0; if(nit>=2 && k>nit-2)k=nit-2; if (nit<2) k=0;
        float wq=0.f;
        if (nit>=2){ float tl=gls[k],tr=gls[k+1]; float den=(tr-tl==0.f)?1.f:(tr-tl); wq=(tq-tl)/den; }
        if (tid<LAT){
            size_t o0 = (size_t)WS_YS + ((size_t)k*B+b)*LAT+tid;
            float zl = wsf[o0]*(1.f-wq) + ((nit>=2)? wsf[o0+(size_t)B*LAT]*wq : 0.f);
            ze[tid]=zl;
            out[1026 + b*LAT + tid] = zl;
        }
        __syncthreads();
        if (tid < 128){
            float hj = bs1[tid];
            #pragma unroll 8
            for (int l=0;l<LAT;++l) hj = fmaf(ze[l], Ws1[l*HID+tid], hj);
            hj = fmaf(age[b], Ws1[LAT*HID+tid], hj);
            hj = fmaxf(hj,0.f);
            float p0 = hj*Ws2[tid*2+0], p1 = hj*Ws2[tid*2+1];
            #pragma unroll
            for (int off=32;off>0;off>>=1){ p0 += __shfl_down(p0,off); p1 += __shfl_down(p1,off); }
            int wv = tid>>6;
            if ((tid&63)==0){ pred[wv*2]=p0; pred[wv*2+1]=p1; }
        }
        __syncthreads();
        if (tid==0){
            out[b*2+0] = bs2[0] + pred[0]+pred[2];
            out[b*2+1] = bs2[1] + pred[1]+pred[3];
        }
    }
}

// ---------------- kernel 7: finalize scalars ----------------
__global__ void k_fin(float* wsf, float* out){
    float n = wsf[WS_NO];
    out[1024] = (n>0.f) ? (wsf[WS_RE]/fmaxf(n,1.f)) : 0.f;
    out[1025] = -0.5f * (wsf[WS_KL] / (float)B);
}

extern "C" void kernel_launch(void* const* d_in, const int* in_sizes, int n_in,
                              void* d_out, int out_size, void* d_ws, size_t ws_size,
                              hipStream_t stream) {
    const float* obs   = (const float*)d_in[0];
    const float* age   = (const float*)d_in[1];
    const float* eps   = (const float*)d_in[2];
    const float* Wih   = (const float*)d_in[3];
    const float* Whh   = (const float*)d_in[4];
    const float* bih   = (const float*)d_in[5];
    const float* bhh   = (const float*)d_in[6];
    const float* Wmu   = (const float*)d_in[7];
    const float* bmu   = (const float*)d_in[8];
    const float* Wlv   = (const float*)d_in[9];
    const float* blv   = (const float*)d_in[10];
    const float* W1    = (const float*)d_in[11];
    const float* b1    = (const float*)d_in[12];
    const float* W2    = (const float*)d_in[13];
    const float* b2    = (const float*)d_in[14];
    const float* W3    = (const float*)d_in[15];
    const float* b3    = (const float*)d_in[16];
    const float* Wo1   = (const float*)d_in[17];
    const float* bo1   = (const float*)d_in[18];
    const float* Wo2   = (const float*)d_in[19];
    const float* bo2   = (const float*)d_in[20];
    const float* Ws1   = (const float*)d_in[21];
    const float* bs1   = (const float*)d_in[22];
    const float* Ws2   = (const float*)d_in[23];
    const float* bs2   = (const float*)d_in[24];
    const int*   maskI = (const int*)d_in[25];
    const int*   tp    = (const int*)d_in[26];
    const int*   seq   = (const int*)d_in[27];
    float* wsf = (float*)d_ws;
    float* out = (float*)d_out;

    k_setup<<<1, 256, 0, stream>>>(tp, wsf);
    k_w31<<<16, 256, 0, stream>>>(W1, W3, b3, wsf);
    k_gru<<<B/16, 512, 0, stream>>>(obs, eps, Wih, Whh, bih, bhh, Wmu, bmu, Wlv, blv,
                                    maskI, tp, wsf);
    k_ode<<<B/16, 512, 0, stream>>>(W1, b1, W2, b2, W3, b3, wsf);
    k_recon<<<B, 512, 0, stream>>>(obs, maskI, tp, seq, Wo1, bo1, Wo2, bo2,
                                   age, Ws1, bs1, Ws2, bs2, wsf, out);
    k_fin<<<1, 1, 0, stream>>>(wsf, out);
}

// Round 10
// 523.839 us; speedup vs baseline: 1.0075x; 1.0075x over previous
//
#include <hip/hip_runtime.h>
#include <hip/hip_bf16.h>
#include <math.h>

#define B 512
#define T 64
#define NL 32
#define LAT 64
#define HID 128
#define DIN 65
#define G3 384
#define FSCALE 365.0f
#define MAXGRID 128

// ws layout (float index)
#define WS_NIT   2   // int
#define WS_KL    3
#define WS_RE    4
#define WS_NO    5
#define WS_CNT   6   // int completion counter
#define WS_GRID  8                 // MAXGRID floats
#define WS_Z0    (WS_GRID + MAXGRID)
#define WS_YS    (WS_Z0 + B*LAT)   // MAXGRID * B * LAT floats
// nit <= 111 always (TMAX=2000 -> ceil((1999/365)/0.05+1) = 111), so ys rows >= 112
// are never written. Reuse rows 112+ for packed weight fragments, row 120 for b31.
// Fragment arrays: layout [frag][role] where role = w*64+lane = tid (512-thread
// consumers), each slot 16B (one bf16x8) -> consumer load is coalesced dwordx4.
#define FR_BASE  (WS_YS + 112*B*LAT)
#define GRU_FR   FR_BASE                    // 18 frags * 512 roles * 4 f32
#define ODE_FR   (GRU_FR + 18*512*4)        // 14 frags
#define REC_FR   (ODE_FR + 14*512*4)        // 6 frags
#define WS_B31   (WS_YS + 120*B*LAT)        // 128 f32

typedef __attribute__((ext_vector_type(8))) __bf16 bf16x8;
typedef __attribute__((ext_vector_type(4))) float f32x4;

#define SWZ(row) ((((row)>>3)&1)<<5)

static __device__ __forceinline__ float tanh_fast(float x){
    float t = __builtin_amdgcn_exp2f(x * 2.8853900817779268f);
    return 1.0f - 2.0f * __builtin_amdgcn_rcpf(t + 1.0f);
}
static __device__ __forceinline__ float sigmoid_fast(float x){
    return __builtin_amdgcn_rcpf(1.0f + __builtin_amdgcn_exp2f(-1.4426950408889634f * x));
}
// LDS-only barrier: drains lgkmcnt but not vmcnt.
static __device__ __forceinline__ void bar_lds(){
    asm volatile("" ::: "memory");
    asm volatile("s_waitcnt lgkmcnt(0)" ::: "memory");
    __builtin_amdgcn_s_barrier();
    asm volatile("" ::: "memory");
}

// ---------------- kernel 1: prep — setup (block 8) + fragment packing (blocks 0-7) ----
// Blocks 0-7: 256 threads = (q' = tid>>6, lane = tid&63); role = blockIdx*64+lane.
// Packs gru/ode/recon weight fragments; computes W31 frags via LDS-staged dots.
__global__ __launch_bounds__(256) void k_prep(
    const int* __restrict__ tp,
    const float* __restrict__ Wih, const float* __restrict__ Whh,
    const float* __restrict__ W1,  const float* __restrict__ W2,
    const float* __restrict__ W3,  const float* __restrict__ b3,
    const float* __restrict__ Wo1, const float* __restrict__ Wo2,
    float* wsf)
{
    int* wsi = (int*)wsf;
    const int tid = threadIdx.x;
    if (blockIdx.x == 8){
        // ---- setup: min/max of tp, grid, accumulators ----
        __shared__ int smin[256], smax[256];
        int mn = 2147483647, mx = -2147483647-1;
        for (int i = tid; i < B*T; i += 256){ int v = tp[i]; mn = min(mn,v); mx = max(mx,v); }
        smin[tid]=mn; smax[tid]=mx; __syncthreads();
        for (int s=128; s>0; s>>=1){
            if (tid<s){ smin[tid]=min(smin[tid],smin[tid+s]); smax[tid]=max(smax[tid],smax[tid+s]); }
            __syncthreads();
        }
        float t0f = (float)smin[0] / FSCALE;
        float t1f = (float)smax[0] / FSCALE;
        double t0d = (double)t0f, t1d = (double)t1f;
        int nit = (int)ceil((t1d-t0d)/0.05 + 1.0);
        if (nit < 1) nit = 1;
        if (nit > MAXGRID) nit = MAXGRID;
        if (tid==0){
            wsi[WS_NIT] = nit; wsi[WS_CNT] = 0;
            wsf[WS_KL]=0.f; wsf[WS_RE]=0.f; wsf[WS_NO]=0.f;
        }
        if (tid < nit){
            double g = (double)tid * 0.05 + t0d;
            if (tid == nit-1 && g > t1d) g = t1d;
            wsf[WS_GRID + tid] = (float)g;
        }
        return;
    }
    // ---- fragment packing ----
    const int w = blockIdx.x;          // 0..7
    const int qp = tid >> 6;           // 0..3
    const int lane = tid & 63;
    const int g = lane >> 4, c = lane & 15;
    const int hc = 16*w + c;
    const int lc = 16*(w&3) + c;
    const int role = w*64 + lane;
    __shared__ float W1l[64][HID];     // 32KB
    __shared__ float W3l[HID][64];     // 32KB
    for (int i = tid; i < 64*HID/4; i += 256)
        ((float4*)&W1l[0][0])[i] = ((const float4*)W1)[i];
    for (int i = tid; i < HID*64/4; i += 256)
        ((float4*)&W3l[0][0])[i] = ((const float4*)W3)[i];
    __syncthreads();

    // GRU fused r/z frags: q in {qp} ∪ {4+qp | qp<2}
    {
        int qlist[2]; int nq = 0;
        qlist[nq++] = qp;
        if (qp < 2) qlist[nq++] = 4+qp;
        for (int ii=0; ii<nq; ++ii){
            int q = qlist[ii];
            int kt = q<2 ? q : q+1;
            bf16x8 vr8, vz8;
            #pragma unroll
            for (int e=0;e<8;++e){
                int k = kt*32 + g*8 + e;
                float vr, vz;
                if (k < 64){ vr = Wih[k*G3 + hc];      vz = Wih[k*G3 + 128+hc]; }
                else       { vr = Whh[(k-96)*G3 + hc]; vz = Whh[(k-96)*G3 + 128+hc]; }
                vr8[e] = (__bf16)vr; vz8[e] = (__bf16)vz;
            }
            *(bf16x8*)&wsf[GRU_FR + ((q)*512 + role)*4]   = vr8;
            *(bf16x8*)&wsf[GRU_FR + ((6+q)*512 + role)*4] = vz8;
        }
    }
    if (qp < 2){  // wi[qp]
        bf16x8 v;
        #pragma unroll
        for (int e=0;e<8;++e) v[e] = (__bf16)Wih[(qp*32+g*8+e)*G3 + 256+hc];
        *(bf16x8*)&wsf[GRU_FR + ((12+qp)*512 + role)*4] = v;
    }
    {   // wh[qp]
        bf16x8 v;
        #pragma unroll
        for (int e=0;e<8;++e) v[e] = (__bf16)Whh[(qp*32+g*8+e)*G3 + 256+hc];
        *(bf16x8*)&wsf[GRU_FR + ((14+qp)*512 + role)*4] = v;
    }
    // ODE: w2f[qp], w31f[qp], w3f[qp], w1f[qp<2]
    {
        bf16x8 v;
        #pragma unroll
        for (int e=0;e<8;++e) v[e] = (__bf16)W2[(qp*32+g*8+e)*HID + hc];
        *(bf16x8*)&wsf[ODE_FR + ((qp)*512 + role)*4] = v;
    }
    {
        bf16x8 v;
        #pragma unroll
        for (int e=0;e<8;++e){
            int k = qp*32 + g*8 + e;
            float a0=0.f, a1=0.f;
            #pragma unroll 4
            for (int l=0;l<64;l+=2){
                a0 = fmaf(W3l[k][l],   W1l[l][hc],   a0);
                a1 = fmaf(W3l[k][l+1], W1l[l+1][hc], a1);
            }
            v[e] = (__bf16)(a0+a1);
        }
        *(bf16x8*)&wsf[ODE_FR + ((4+qp)*512 + role)*4] = v;
    }
    {
        bf16x8 v;
        #pragma unroll
        for (int e=0;e<8;++e) v[e] = (__bf16)W3l[qp*32+g*8+e][lc];
        *(bf16x8*)&wsf[ODE_FR + ((8+qp)*512 + role)*4] = v;
    }
    if (qp < 2){
        bf16x8 v;
        #pragma unroll
        for (int e=0;e<8;++e) v[e] = (__bf16)W1l[qp*32+g*8+e][hc];
        *(bf16x8*)&wsf[ODE_FR + ((12+qp)*512 + role)*4] = v;
    }
    // RECON: wo1f[qp<2], wo2f[qp]
    if (qp < 2){
        bf16x8 v;
        #pragma unroll
        for (int e=0;e<8;++e) v[e] = (__bf16)Wo1[(qp*32+g*8+e)*HID + hc];
        *(bf16x8*)&wsf[REC_FR + ((qp)*512 + role)*4] = v;
    }
    {
        bf16x8 v;
        #pragma unroll
        for (int e=0;e<8;++e) v[e] = (__bf16)Wo2[(qp*32+g*8+e)*NL + 16*(w&1)+c];
        *(bf16x8*)&wsf[REC_FR + ((2+qp)*512 + role)*4] = v;
    }
    // b31[hc] = dot(b3, W1 col hc)  (one thread per hc)
    if (qp == 3 && g == 0){
        float a = 0.f;
        #pragma unroll 8
        for (int l=0;l<64;++l) a = fmaf(b3[l], W1l[l][hc], a);
        wsf[WS_B31 + hc] = a;
    }
}

// ---------------- kernel 3: GRU encoder via MFMA (16 rows/block, 8 waves) ----------------
__global__ __launch_bounds__(512) void k_gru(
    const float* __restrict__ obs, const float* __restrict__ eps,
    const float* __restrict__ bih, const float* __restrict__ bhh,
    const float* __restrict__ Wih,
    const float* __restrict__ Wmu, const float* __restrict__ bmu,
    const float* __restrict__ Wlv, const float* __restrict__ blv,
    const int* __restrict__ maskI, const int* __restrict__ tp,
    float* wsf)
{
    const int b0 = blockIdx.x * 16;
    const int tid = threadIdx.x;
    const int w = tid >> 6, lane = tid & 63;
    const int g = lane >> 4, c = lane & 15;
    const int xr = tid >> 5, xl = tid & 31;

    __shared__ __align__(16) __bf16 xh[16][232];   // stride 464B
    __shared__ int   tps[16][64];
    __shared__ float dts[16];
    __shared__ float lvs[16][64];
    __shared__ float red[8];
    char* xbase = (char*)&xh[0][0];
    #define XH_RD(row, bytecol) (*(const bf16x8*)(xbase + (row)*464 + ((bytecol) ^ SWZ(row))))
    #define XH_WPTR(row, bytecol) ((__bf16*)(xbase + (row)*464 + ((bytecol) ^ SWZ(row))))

    ((int2*)tps)[tid] = ((const int2*)(tp + (size_t)b0*T))[tid];
    {
        unsigned* xz = (unsigned*)xbase;
        #pragma unroll
        for (int i=0;i<1856;i+=512) xz[i+tid] = 0u;
    }

    // ---- coalesced fragment loads (packed by k_prep) ----
    bf16x8 wr[6], wz[6], wi[2], wh[4];
    {
        const bf16x8* gfr = (const bf16x8*)&wsf[GRU_FR];
        #pragma unroll
        for (int q=0;q<6;++q) wr[q] = gfr[q*512 + tid];
        #pragma unroll
        for (int q=0;q<6;++q) wz[q] = gfr[(6+q)*512 + tid];
        #pragma unroll
        for (int q=0;q<2;++q) wi[q] = gfr[(12+q)*512 + tid];
        #pragma unroll
        for (int q=0;q<4;++q) wh[q] = gfr[(14+q)*512 + tid];
    }
    const float wdr = Wih[64*G3 + 16*w+c];
    const float wdz = Wih[64*G3 + 128+16*w+c];
    const float wdn = Wih[64*G3 + 256+16*w+c];
    const float rb  = bih[16*w+c]     + bhh[16*w+c];
    const float zb  = bih[128+16*w+c] + bhh[128+16*w+c];
    const float inb = bih[256+16*w+c];
    const float hnb = bhh[256+16*w+c];

    __syncthreads();

    {
        float mv = (float)maskI[((size_t)(b0+xr)*T + 63)*NL + xl];
        float ov = obs[((size_t)(b0+xr)*T + 63)*NL + xl];
        *XH_WPTR(xr, 2*xl)      = (__bf16)(ov*mv);
        *XH_WPTR(xr, 64 + 2*xl) = (__bf16)mv;
        if (xl==0) dts[xr] = (float)(tps[xr][63]-tps[xr][62]);
    }
    float ovP = 0.f, mvP = 0.f;
    {
        mvP = (float)maskI[((size_t)(b0+xr)*T + 62)*NL + xl];
        ovP = obs[((size_t)(b0+xr)*T + 62)*NL + xl];
    }

    float hold[4] = {0.f,0.f,0.f,0.f};

    for (int s=0;s<T;++s){
        bar_lds();
        bf16x8 A0 = XH_RD(c, 0   + 16*g);
        bf16x8 A1 = XH_RD(c, 64  + 16*g);
        bf16x8 A2 = XH_RD(c, 192 + 16*g);
        bf16x8 A3 = XH_RD(c, 256 + 16*g);
        bf16x8 A4 = XH_RD(c, 320 + 16*g);
        bf16x8 A5 = XH_RD(c, 384 + 16*g);
        const float dt0=dts[4*g], dt1=dts[4*g+1], dt2=dts[4*g+2], dt3=dts[4*g+3];
        float ovN=0.f, mvN=0.f; const int t2 = 61-s;
        if (t2 >= 0){
            mvN = (float)maskI[((size_t)(b0+xr)*T + t2)*NL + xl];
            ovN = obs[((size_t)(b0+xr)*T + t2)*NL + xl];
        }
        f32x4 racc={0,0,0,0}, zacc={0,0,0,0}, inacc={0,0,0,0}, hnacc={0,0,0,0};
        racc  = __builtin_amdgcn_mfma_f32_16x16x32_bf16(A0, wr[0], racc, 0,0,0);
        zacc  = __builtin_amdgcn_mfma_f32_16x16x32_bf16(A0, wz[0], zacc, 0,0,0);
        inacc = __builtin_amdgcn_mfma_f32_16x16x32_bf16(A0, wi[0], inacc,0,0,0);
        hnacc = __builtin_amdgcn_mfma_f32_16x16x32_bf16(A2, wh[0], hnacc,0,0,0);
        racc  = __builtin_amdgcn_mfma_f32_16x16x32_bf16(A1, wr[1], racc, 0,0,0);
        zacc  = __builtin_amdgcn_mfma_f32_16x16x32_bf16(A1, wz[1], zacc, 0,0,0);
        inacc = __builtin_amdgcn_mfma_f32_16x16x32_bf16(A1, wi[1], inacc,0,0,0);
        hnacc = __builtin_amdgcn_mfma_f32_16x16x32_bf16(A3, wh[1], hnacc,0,0,0);
        racc  = __builtin_amdgcn_mfma_f32_16x16x32_bf16(A2, wr[2], racc, 0,0,0);
        zacc  = __builtin_amdgcn_mfma_f32_16x16x32_bf16(A2, wz[2], zacc, 0,0,0);
        hnacc = __builtin_amdgcn_mfma_f32_16x16x32_bf16(A4, wh[2], hnacc,0,0,0);
        racc  = __builtin_amdgcn_mfma_f32_16x16x32_bf16(A3, wr[3], racc, 0,0,0);
        zacc  = __builtin_amdgcn_mfma_f32_16x16x32_bf16(A3, wz[3], zacc, 0,0,0);
        hnacc = __builtin_amdgcn_mfma_f32_16x16x32_bf16(A5, wh[3], hnacc,0,0,0);
        racc  = __builtin_amdgcn_mfma_f32_16x16x32_bf16(A4, wr[4], racc, 0,0,0);
        zacc  = __builtin_amdgcn_mfma_f32_16x16x32_bf16(A4, wz[4], zacc, 0,0,0);
        racc  = __builtin_amdgcn_mfma_f32_16x16x32_bf16(A5, wr[5], racc, 0,0,0);
        zacc  = __builtin_amdgcn_mfma_f32_16x16x32_bf16(A5, wz[5], zacc, 0,0,0);
        float hnew[4]; const float dtv[4] = {dt0,dt1,dt2,dt3};
        #pragma unroll
        for (int j=0;j<4;++j){
            float dv = dtv[j];
            float r  = sigmoid_fast(racc[j] + rb + dv*wdr);
            float zg = sigmoid_fast(zacc[j] + zb + dv*wdz);
            float n  = tanh_fast(inacc[j] + inb + dv*wdn + r*(hnacc[j] + hnb));
            float hv = (1.f - zg)*n + zg*hold[j];
            hold[j] = hv; hnew[j] = hv;
        }
        bar_lds();
        #pragma unroll
        for (int j=0;j<4;++j)
            *XH_WPTR(4*g+j, 192 + 2*(16*w+c)) = (__bf16)hnew[j];
        if (s < T-1){
            const int tn = 62 - s;
            *XH_WPTR(xr, 2*xl)      = (__bf16)(ovP*mvP);
            *XH_WPTR(xr, 64 + 2*xl) = (__bf16)mvP;
            if (xl==0) dts[xr] = (tn>0) ? (float)(tps[xr][tn]-tps[xr][tn-1]) : 0.f;
        }
        ovP = ovN; mvP = mvN;
    }
    __syncthreads();

    const int col4 = 16*(w&3)+c;
    bf16x8 Ah0 = XH_RD(c, 192 + 0   + 16*g);
    bf16x8 Ah1 = XH_RD(c, 192 + 64  + 16*g);
    bf16x8 Ah2 = XH_RD(c, 192 + 128 + 16*g);
    bf16x8 Ah3 = XH_RD(c, 192 + 192 + 16*g);
    const float* Wm = (w<4)? Wmu : Wlv;
    f32x4 acc={0,0,0,0};
    {
        bf16x8 bf0,bf1,bf2,bf3;
        #pragma unroll
        for (int e=0;e<8;++e){
            bf0[e] = (__bf16)Wm[(0*32+g*8+e)*LAT + col4];
            bf1[e] = (__bf16)Wm[(1*32+g*8+e)*LAT + col4];
            bf2[e] = (__bf16)Wm[(2*32+g*8+e)*LAT + col4];
            bf3[e] = (__bf16)Wm[(3*32+g*8+e)*LAT + col4];
        }
        acc = __builtin_amdgcn_mfma_f32_16x16x32_bf16(Ah0, bf0, acc, 0,0,0);
        acc = __builtin_amdgcn_mfma_f32_16x16x32_bf16(Ah1, bf1, acc, 0,0,0);
        acc = __builtin_amdgcn_mfma_f32_16x16x32_bf16(Ah2, bf2, acc, 0,0,0);
        acc = __builtin_amdgcn_mfma_f32_16x16x32_bf16(Ah3, bf3, acc, 0,0,0);
    }
    const float mbias = (w<4)? bmu[col4] : blv[col4];
    if (w>=4){
        #pragma unroll
        for (int j=0;j<4;++j) lvs[4*g+j][col4] = acc[j] + mbias;
    }
    __syncthreads();
    if (w<4){
        float kl = 0.f;
        #pragma unroll
        for (int j=0;j<4;++j){
            float mu = acc[j] + mbias;
            float lv = lvs[4*g+j][col4];
            int row = b0 + 4*g + j;
            float z0 = mu + eps[(size_t)row*LAT + col4]*expf(0.5f*lv);
            wsf[WS_Z0 + (size_t)row*LAT + col4] = z0;
            wsf[WS_YS + (size_t)row*LAT + col4] = z0;
            kl += 1.f + lv - mu*mu - expf(lv);
        }
        #pragma unroll
        for (int off=32; off>0; off>>=1) kl += __shfl_xor(kl, off);
        if (lane==0) red[w] = kl;
    }
    __syncthreads();
    if (tid==0) atomicAdd(&wsf[WS_KL], red[0]+red[1]+red[2]+red[3]);
    #undef XH_RD
    #undef XH_WPTR
}

// ---------------- kernel 4: RK4 ODE, 2-phase fused, 8 waves, swizzled LDS ----------
__global__ __launch_bounds__(512) void k_ode(
    const float* __restrict__ b1, const float* __restrict__ b2,
    const float* __restrict__ b3, float* wsf)
{
    const int b0 = blockIdx.x * 16;
    const int tid = threadIdx.x;
    const int w = tid >> 6, lane = tid & 63;
    const int g = lane >> 4, c = lane & 15;
    const int hc = 16*w + c;
    const int lc = 16*(w&3) + c;
    const int* wsi = (const int*)wsf;
    const int nit = wsi[WS_NIT];

    __shared__ __align__(16) __bf16 Gl[16][136];   // stride 272B
    __shared__ __align__(16) __bf16 Hl[16][136];
    __shared__ float gls[MAXGRID];
    char* gbase = (char*)&Gl[0][0];
    char* hbase = (char*)&Hl[0][0];
    #define LDS_RD(base, row, bytecol) (*(const bf16x8*)((base) + (row)*272 + ((bytecol) ^ SWZ(row))))
    #define LDS_WPTR(base, row, bytecol) ((__bf16*)((base) + (row)*272 + ((bytecol) ^ SWZ(row))))

    // ---- coalesced fragment loads ----
    bf16x8 w2f[4], w31f[4], w3f[4], w1f0, w1f1;
    {
        const bf16x8* ofr = (const bf16x8*)&wsf[ODE_FR];
        #pragma unroll
        for (int q=0;q<4;++q) w2f[q]  = ofr[q*512 + tid];
        #pragma unroll
        for (int q=0;q<4;++q) w31f[q] = ofr[(4+q)*512 + tid];
        #pragma unroll
        for (int q=0;q<4;++q) w3f[q]  = ofr[(8+q)*512 + tid];
        w1f0 = ofr[12*512 + tid];
        w1f1 = ofr[13*512 + tid];
    }
    const float b1v  = b1[hc];
    const float b2v  = b2[hc];
    const float b31v = wsf[WS_B31 + hc];
    const float b3v  = b3[lc];

    for (int kk=tid; kk<MAXGRID; kk+=512) gls[kk]=wsf[WS_GRID+kk];

    // stage z0 + y init
    {
        int r = tid >> 5, l0 = (tid & 31)*2;
        float2 zv = *(const float2*)&wsf[WS_Z0 + (size_t)(b0+r)*LAT + l0];
        __bf16* p = LDS_WPTR(gbase, r, 2*l0);
        p[0] = (__bf16)zv.x;
        p[1] = (__bf16)zv.y;
    }
    float y[4];
    #pragma unroll
    for (int j=0;j<4;++j)
        y[j] = wsf[WS_Z0 + (size_t)(b0+4*g+j)*LAT + lc];
    __syncthreads();

    // U = z0 @ W1
    f32x4 U;
    {
        bf16x8 az0 = LDS_RD(gbase, c, 16*g);
        bf16x8 az1 = LDS_RD(gbase, c, 64 + 16*g);
        f32x4 a = {0.f,0.f,0.f,0.f};
        a = __builtin_amdgcn_mfma_f32_16x16x32_bf16(az0, w1f0, a, 0,0,0);
        a = __builtin_amdgcn_mfma_f32_16x16x32_bf16(az1, w1f1, a, 0,0,0);
        U = a;
    }
    __syncthreads();

    #pragma unroll
    for (int j=0;j<4;++j)
        *LDS_WPTR(gbase, 4*g+j, 2*hc) = (__bf16)tanh_fast(U[j] + b1v);
    __syncthreads();

    f32x4 Uacc={0,0,0,0}, faccv={0,0,0,0};

    for (int i=0; i<nit-1; ++i){
        const float h = gls[i+1]-gls[i];
        #pragma unroll
        for (int sub=0; sub<4; ++sub){
            // phase B: H2 = tanh(G @ W2 + b2)
            {
                bf16x8 a0 = LDS_RD(gbase, c, 0   + 16*g);
                bf16x8 a1 = LDS_RD(gbase, c, 64  + 16*g);
                bf16x8 a2 = LDS_RD(gbase, c, 128 + 16*g);
                bf16x8 a3 = LDS_RD(gbase, c, 192 + 16*g);
                __builtin_amdgcn_s_setprio(1);
                f32x4 ca={0,0,0,0}, cb={0,0,0,0};
                ca = __builtin_amdgcn_mfma_f32_16x16x32_bf16(a0, w2f[0], ca, 0,0,0);
                cb = __builtin_amdgcn_mfma_f32_16x16x32_bf16(a2, w2f[2], cb, 0,0,0);
                ca = __builtin_amdgcn_mfma_f32_16x16x32_bf16(a1, w2f[1], ca, 0,0,0);
                cb = __builtin_amdgcn_mfma_f32_16x16x32_bf16(a3, w2f[3], cb, 0,0,0);
                __builtin_amdgcn_s_setprio(0);
                #pragma unroll
                for (int j=0;j<4;++j)
                    *LDS_WPTR(hbase, 4*g+j, 2*hc) = (__bf16)tanh_fast(ca[j]+cb[j]+b2v);
            }
            bar_lds();
            // phase C: V' = H2@W31+b31 (all), F = H2@W3+b3 (waves 0-3), RK4
            {
                bf16x8 h0 = LDS_RD(hbase, c, 0   + 16*g);
                bf16x8 h1 = LDS_RD(hbase, c, 64  + 16*g);
                bf16x8 h2 = LDS_RD(hbase, c, 128 + 16*g);
                bf16x8 h3 = LDS_RD(hbase, c, 192 + 16*g);
                __builtin_amdgcn_s_setprio(1);
                f32x4 va={0,0,0,0}, vb={0,0,0,0};
                va = __builtin_amdgcn_mfma_f32_16x16x32_bf16(h0, w31f[0], va, 0,0,0);
                vb = __builtin_amdgcn_mfma_f32_16x16x32_bf16(h2, w31f[2], vb, 0,0,0);
                va = __builtin_amdgcn_mfma_f32_16x16x32_bf16(h1, w31f[1], va, 0,0,0);
                vb = __builtin_amdgcn_mfma_f32_16x16x32_bf16(h3, w31f[3], vb, 0,0,0);
                f32x4 fv = {0,0,0,0};
                if (w < 4){
                    f32x4 fa={0,0,0,0}, fb={0,0,0,0};
                    fa = __builtin_amdgcn_mfma_f32_16x16x32_bf16(h0, w3f[0], fa, 0,0,0);
                    fb = __builtin_amdgcn_mfma_f32_16x16x32_bf16(h2, w3f[2], fb, 0,0,0);
                    fa = __builtin_amdgcn_mfma_f32_16x16x32_bf16(h1, w3f[1], fa, 0,0,0);
                    fb = __builtin_amdgcn_mfma_f32_16x16x32_bf16(h3, w3f[3], fb, 0,0,0);
                    #pragma unroll
                    for (int j=0;j<4;++j) fv[j] = fa[j] + fb[j] + b3v;
                }
                __builtin_amdgcn_s_setprio(0);
                f32x4 V;
                #pragma unroll
                for (int j=0;j<4;++j) V[j] = va[j] + vb[j] + b31v;

                if (sub==0){ Uacc = V; faccv = fv; }
                else if (sub==3){ Uacc += V; faccv += fv; }
                else { Uacc += 2.f*V; faccv += 2.f*fv; }

                if (sub < 3){
                    const float al = (sub==2) ? h : 0.5f*h;
                    #pragma unroll
                    for (int j=0;j<4;++j)
                        *LDS_WPTR(gbase, 4*g+j, 2*hc) = (__bf16)tanh_fast(fmaf(al, V[j], U[j]) + b1v);
                } else {
                    const float h6 = h*(1.0f/6.0f);
                    if (w < 4){
                        #pragma unroll
                        for (int j=0;j<4;++j){
                            y[j] = fmaf(h6, faccv[j], y[j]);
                            wsf[WS_YS + ((size_t)(i+1)*B + (b0+4*g+j))*LAT + lc] = y[j];
                        }
                    }
                    #pragma unroll
                    for (int j=0;j<4;++j){
                        U[j] = fmaf(h6, Uacc[j], U[j]);
                        *LDS_WPTR(gbase, 4*g+j, 2*hc) = (__bf16)tanh_fast(U[j] + b1v);
                    }
                }
            }
            bar_lds();
        }
    }
    #undef LDS_RD
    #undef LDS_WPTR
}

// ---------------- kernel 5: recon + surv + finalize (1 block per b, 8 waves) ----------
__global__ __launch_bounds__(512) void k_recon(
    const float* __restrict__ obs, const int* __restrict__ maskI,
    const int* __restrict__ tp, const int* __restrict__ seq,
    const float* __restrict__ bo1, const float* __restrict__ bo2,
    const float* __restrict__ age,
    const float* __restrict__ Ws1, const float* __restrict__ bs1,
    const float* __restrict__ Ws2, const float* __restrict__ bs2,
    float* wsf, float* out)
{
    const int b = blockIdx.x, tid = threadIdx.x;
    const int w = tid >> 6, lane = tid & 63;
    const int g = lane >> 4, c = lane & 15;
    __shared__ __align__(16) __bf16 zbt[64][72];
    __shared__ __align__(16) __bf16 hb[64][136];
    __shared__ float gls[MAXGRID];
    __shared__ float red[16];
    __shared__ float ze[64];
    __shared__ float pred[4];
    const int* wsi=(const int*)wsf;
    const int nit = wsi[WS_NIT];
    for (int i=tid;i<MAXGRID;i+=512) gls[i]=wsf[WS_GRID+i];

    // ---- coalesced fragment loads ----
    bf16x8 wo1f[2], wo2f[4];
    {
        const bf16x8* rfr = (const bf16x8*)&wsf[REC_FR];
        wo1f[0] = rfr[0*512 + tid];
        wo1f[1] = rfr[1*512 + tid];
        #pragma unroll
        for (int q=0;q<4;++q) wo2f[q] = rfr[(2+q)*512 + tid];
    }
    const float bo1v = bo1[16*w+c];
    const float bo2v = bo2[16*(w&1)+c];
    const int sl = seq[b];
    __syncthreads();

    {
        int t = tid >> 3, seg = tid & 7;
        float tq = (float)tp[b*T+t] / FSCALE;
        int lo=0, hi=nit;
        while (lo<hi){ int mid=(lo+hi)>>1; if (gls[mid]<=tq) lo=mid+1; else hi=mid; }
        int k = lo-1; if (k<0) k=0; if (nit>=2 && k>nit-2) k=nit-2; if (nit<2) k=0;
        float wq=0.f;
        if (nit>=2){ float tl=gls[k], tr=gls[k+1]; float den=(tr-tl==0.f)?1.f:(tr-tl); wq=(tq-tl)/den; }
        size_t o0 = (size_t)WS_YS + ((size_t)k*B + b)*LAT + seg*8;
        float4 za0 = *(const float4*)&wsf[o0];
        float4 za1 = *(const float4*)&wsf[o0+4];
        float4 zb0, zb1;
        if (nit>=2){
            zb0 = *(const float4*)&wsf[o0 + (size_t)B*LAT];
            zb1 = *(const float4*)&wsf[o0 + (size_t)B*LAT + 4];
        } else { zb0 = za0; zb1 = za1; }
        __bf16* dst = &zbt[t][seg*8];
        dst[0] = (__bf16)(za0.x*(1.f-wq)+zb0.x*wq);
        dst[1] = (__bf16)(za0.y*(1.f-wq)+zb0.y*wq);
        dst[2] = (__bf16)(za0.z*(1.f-wq)+zb0.z*wq);
        dst[3] = (__bf16)(za0.w*(1.f-wq)+zb0.w*wq);
        dst[4] = (__bf16)(za1.x*(1.f-wq)+zb1.x*wq);
        dst[5] = (__bf16)(za1.y*(1.f-wq)+zb1.y*wq);
        dst[6] = (__bf16)(za1.z*(1.f-wq)+zb1.z*wq);
        dst[7] = (__bf16)(za1.w*(1.f-wq)+zb1.w*wq);
    }
    __syncthreads();

    #pragma unroll
    for (int m=0;m<4;++m){
        f32x4 acc = {0.f,0.f,0.f,0.f};
        bf16x8 a0 = *(const bf16x8*)&zbt[16*m+c][g*8];
        bf16x8 a1 = *(const bf16x8*)&zbt[16*m+c][32+g*8];
        acc = __builtin_amdgcn_mfma_f32_16x16x32_bf16(a0, wo1f[0], acc, 0,0,0);
        acc = __builtin_amdgcn_mfma_f32_16x16x32_bf16(a1, wo1f[1], acc, 0,0,0);
        #pragma unroll
        for (int j=0;j<4;++j)
            hb[16*m+4*g+j][16*w+c] = (__bf16)fmaxf(acc[j] + bo1v, 0.f);
    }
    __syncthreads();

    float esum = 0.f, ncnt = 0.f;
    {
        int m = w >> 1, n = w & 1;
        f32x4 ca = {0.f,0.f,0.f,0.f}, cb = {0.f,0.f,0.f,0.f};
        bf16x8 a0 = *(const bf16x8*)&hb[16*m+c][g*8];
        bf16x8 a1 = *(const bf16x8*)&hb[16*m+c][32+g*8];
        bf16x8 a2 = *(const bf16x8*)&hb[16*m+c][64+g*8];
        bf16x8 a3 = *(const bf16x8*)&hb[16*m+c][96+g*8];
        ca = __builtin_amdgcn_mfma_f32_16x16x32_bf16(a0, wo2f[0], ca, 0,0,0);
        cb = __builtin_amdgcn_mfma_f32_16x16x32_bf16(a2, wo2f[2], cb, 0,0,0);
        ca = __builtin_amdgcn_mfma_f32_16x16x32_bf16(a1, wo2f[1], ca, 0,0,0);
        cb = __builtin_amdgcn_mfma_f32_16x16x32_bf16(a3, wo2f[3], cb, 0,0,0);
        #pragma unroll
        for (int j=0;j<4;++j){
            int t = 16*m + 4*g + j;
            int col = 16*n + c;
            float xh2 = (ca[j]+cb[j]) + bo2v;
            float mv = (float)maskI[(b*T+t)*NL+col] * ((t<sl)?1.f:0.f);
            float d = xh2 - obs[(b*T+t)*NL+col];
            esum = fmaf(mv*d, d, esum);
            ncnt += mv;
        }
    }
    #pragma unroll
    for (int off=32; off>0; off>>=1){
        esum += __shfl_xor(esum, off);
        ncnt += __shfl_xor(ncnt, off);
    }
    if (lane==0){ red[w] = esum; red[8+w] = ncnt; }
    __syncthreads();
    if (tid==0){
        float s=0.f, nn=0.f;
        #pragma unroll
        for (int i=0;i<8;++i){ s += red[i]; nn += red[8+i]; }
        atomicAdd(&wsf[WS_RE], s);
        atomicAdd(&wsf[WS_NO], nn);
    }

    // ---- survival head ----
    {
        float tq = (float)tp[b*T + sl-1] / FSCALE;
        int lo=0,hi=nit;
        while(lo<hi){int mid=(lo+hi)>>1; if (gls[mid]<=tq) lo=mid+1; else hi=mid;}
        int k=lo-1; if(k<0)k=0; if(nit>=2 && k>nit-2)k=nit-2; if (nit<2) k=0;
        float wq=0.f;
        if (nit>=2){ float tl=gls[k],tr=gls[k+1]; float den=(tr-tl==0.f)?1.f:(tr-tl); wq=(tq-tl)/den; }
        if (tid<LAT){
            size_t o0 = (size_t)WS_YS + ((size_t)k*B+b)*LAT+tid;
            float zl = wsf[o0]*(1.f-wq) + ((nit>=2)? wsf[o0+(size_t)B*LAT]*wq : 0.f);
            ze[tid]=zl;
            out[1026 + b*LAT + tid] = zl;
        }
        __syncthreads();
        if (tid < 128){
            float hj = bs1[tid];
            #pragma unroll 8
            for (int l=0;l<LAT;++l) hj = fmaf(ze[l], Ws1[l*HID+tid], hj);
            hj = fmaf(age[b], Ws1[LAT*HID+tid], hj);
            hj = fmaxf(hj,0.f);
            float p0 = hj*Ws2[tid*2+0], p1 = hj*Ws2[tid*2+1];
            #pragma unroll
            for (int off=32;off>0;off>>=1){ p0 += __shfl_down(p0,off); p1 += __shfl_down(p1,off); }
            int wv = tid>>6;
            if ((tid&63)==0){ pred[wv*2]=p0; pred[wv*2+1]=p1; }
        }
        __syncthreads();
        if (tid==0){
            out[b*2+0] = bs2[0] + pred[0]+pred[2];
            out[b*2+1] = bs2[1] + pred[1]+pred[3];
        }
    }

    // ---- finalize (last block to finish) ----
    if (tid==0){
        __threadfence();
        int prev = atomicAdd((int*)wsf + WS_CNT, 1);
        if (prev == B-1){
            float re = atomicAdd(&wsf[WS_RE], 0.f);
            float no = atomicAdd(&wsf[WS_NO], 0.f);
            float kl = atomicAdd(&wsf[WS_KL], 0.f);
            out[1024] = (no>0.f) ? (re/fmaxf(no,1.f)) : 0.f;
            out[1025] = -0.5f * (kl / (float)B);
        }
    }
}

extern "C" void kernel_launch(void* const* d_in, const int* in_sizes, int n_in,
                              void* d_out, int out_size, void* d_ws, size_t ws_size,
                              hipStream_t stream) {
    const float* obs   = (const float*)d_in[0];
    const float* age   = (const float*)d_in[1];
    const float* eps   = (const float*)d_in[2];
    const float* Wih   = (const float*)d_in[3];
    const float* Whh   = (const float*)d_in[4];
    const float* bih   = (const float*)d_in[5];
    const float* bhh   = (const float*)d_in[6];
    const float* Wmu   = (const float*)d_in[7];
    const float* bmu   = (const float*)d_in[8];
    const float* Wlv   = (const float*)d_in[9];
    const float* blv   = (const float*)d_in[10];
    const float* W1    = (const float*)d_in[11];
    const float* b1    = (const float*)d_in[12];
    const float* W2    = (const float*)d_in[13];
    const float* b2    = (const float*)d_in[14];
    const float* W3    = (const float*)d_in[15];
    const float* b3    = (const float*)d_in[16];
    const float* Wo1   = (const float*)d_in[17];
    const float* bo1   = (const float*)d_in[18];
    const float* Wo2   = (const float*)d_in[19];
    const float* bo2   = (const float*)d_in[20];
    const float* Ws1   = (const float*)d_in[21];
    const float* bs1   = (const float*)d_in[22];
    const float* Ws2   = (const float*)d_in[23];
    const float* bs2   = (const float*)d_in[24];
    const int*   maskI = (const int*)d_in[25];
    const int*   tp    = (const int*)d_in[26];
    const int*   seq   = (const int*)d_in[27];
    float* wsf = (float*)d_ws;
    float* out = (float*)d_out;

    k_prep<<<9, 256, 0, stream>>>(tp, Wih, Whh, W1, W2, W3, b3, Wo1, Wo2, wsf);
    k_gru<<<B/16, 512, 0, stream>>>(obs, eps, bih, bhh, Wih, Wmu, bmu, Wlv, blv,
                                    maskI, tp, wsf);
    k_ode<<<B/16, 512, 0, stream>>>(b1, b2, b3, wsf);
    k_recon<<<B, 512, 0, stream>>>(obs, maskI, tp, seq, bo1, bo2,
                                   age, Ws1, bs1, Ws2, bs2, wsf, out);
}